// Round 9
// baseline (437.800 us; speedup 1.0000x reference)
//
#include <hip/hip_runtime.h>
#include <math.h>

// n=16384 Gaussian points in 3D. Exact 12-NN (incl self) per point:
//   out[i] = b + ( (W·p_i)·(1 + 11/sqrt(2)) + 0.5 * sum_{11NN} W·|p_i - p_j| ) / 12
//
// R9: x-bin counting sort (self-zeroing, 1 dispatch), then persistent waves,
// one query per wave grab (atomic queue -> perfect balance):
//   1. seed [t-384, t+384): per-lane MINIMUM only (11 inst/step).
//   2. u = 12th smallest of the 64 lane minima (knockout). Valid UB of the
//      union 12th: the 12 smallest lane-minima are 12 distinct candidates <= u.
//   3. collect-scan seed + march left/right until (x-gap - binwidth)^2 > u:
//      d2 <= u (rare, exec-masked) -> sorted paired (d2,w) insert, 12-deep.
//      Per-lane 12-cap is exact: a dropped entry has 12 smaller same-lane
//      entries, so it cannot be in the union top-12.
//   4. 12-round destructive knockout (first-lane tie-break) extracts the 12
//      smallest collected entries, accumulating their w. Exact "take 12".
//   5. wave-reduce, lane 0 writes. Self contributes w=0.

#define NBINS  2048
#define XMIN_  (-6.0f)
#define INVBW_ ((float)NBINS / 12.0f)
#define SLACK_ ((12.0f / (float)NBINS) * 1.02f)
#define SORTB  64
#define STHR   256
#define BLOCK  256
#define SEED   768
#define KK     12
#define BIG    3.0e38f
#define PADX   1.0e30f

__device__ __forceinline__ int bin_of(float x) {
  int b = (int)((x - XMIN_) * INVBW_);
  b = b < 0 ? 0 : b;
  b = b > NBINS - 1 ? NBINS - 1 : b;
  return b;
}

__device__ __forceinline__ void gbar(int* c, int target) {
  __syncthreads();
  if (threadIdx.x == 0) {
    __threadfence();
    atomicAdd(c, 1);
    while (atomicAdd(c, 0) < target) __builtin_amdgcn_s_sleep(2);
    __threadfence();
  }
  __syncthreads();
}

// sorted ascending paired insert, 12-deep, static indexing (registers)
__device__ __forceinline__ void pinsert(float (&qd)[KK], float (&qw)[KK],
                                        float d, float w) {
#pragma unroll
  for (int k = KK - 1; k >= 1; --k) {
    const bool up  = (qd[k - 1] > d);
    const bool mid = (qd[k] > d);
    const float nd = up ? qd[k - 1] : (mid ? d : qd[k]);
    const float nw = up ? qw[k - 1] : (mid ? w : qw[k]);
    qd[k] = nd; qw[k] = nw;
  }
  if (qd[0] > d) { qw[0] = w; qd[0] = d; }
}

// ---------------- K1: fused counting sort (zero | hist | scan | scatter) -----
__global__ __launch_bounds__(STHR)
void sort_kernel(const float* __restrict__ p, int* __restrict__ hist,
                 int* __restrict__ cursor, int* __restrict__ cnt,
                 float4* __restrict__ sorted, int n) {
  __shared__ int ssum[STHR];
  const int tid = threadIdx.x;
  const int gid = blockIdx.x * STHR + tid;

  for (int i = gid; i < NBINS; i += SORTB * STHR) hist[i] = 0;
  gbar(&cnt[0], SORTB);

  for (int i = gid; i < n; i += SORTB * STHR)
    atomicAdd(&hist[bin_of(p[3 * i])], 1);
  gbar(&cnt[1], SORTB);

  if (blockIdx.x == 0) {
    const int base = tid * (NBINS / STHR);
    int v[NBINS / STHR];
    int sum = 0;
#pragma unroll
    for (int t = 0; t < NBINS / STHR; ++t) { v[t] = hist[base + t]; sum += v[t]; }
    ssum[tid] = sum;
    __syncthreads();
    for (int off = 1; off < STHR; off <<= 1) {
      const int x = (tid >= off) ? ssum[tid - off] : 0;
      __syncthreads();
      ssum[tid] += x;
      __syncthreads();
    }
    int run = (tid > 0) ? ssum[tid - 1] : 0;
#pragma unroll
    for (int t = 0; t < NBINS / STHR; ++t) { cursor[base + t] = run; run += v[t]; }
  }
  gbar(&cnt[2], SORTB);

  for (int i = gid; i < n; i += SORTB * STHR) {
    const float x = p[3 * i], y = p[3 * i + 1], z = p[3 * i + 2];
    const int pos = atomicAdd(&cursor[bin_of(x)], 1);
    sorted[pos] = make_float4(x, y, z, __int_as_float(i));
  }
}

// ---------------- K2: query (persistent waves, one query per grab) -----------
__global__ __launch_bounds__(BLOCK)
void query_kernel(const float4* __restrict__ sv, const float* __restrict__ W,
                  const float* __restrict__ bias, float* __restrict__ out,
                  int* __restrict__ qctr, int n) {
  const int lane = threadIdx.x & 63;
  const float W0 = W[0], W1 = W[1], W2 = W[2];
  const float bb = bias[0];

  for (;;) {
    int t;
    if (lane == 0) t = atomicAdd(qctr, 1);
    t = __shfl(t, 0);
    if (t >= n) break;

    const float4 me = sv[t];
    const float xi = me.x, yi = me.y, zi = me.z;
    const int orig = __float_as_int(me.w);

    int lo = t - SEED / 2;
    lo = lo < 0 ? 0 : lo;
    lo = lo > n - SEED ? n - SEED : lo;
    const float4* base = sv + lo + lane;

    // ---- 1. seed lane-minima (all positions valid) ----
    float m = BIG;
#pragma unroll
    for (int s = 0; s < SEED / 64; ++s) {
      const float4 c = base[s * 64];
      const float dx = xi - c.x, dy = yi - c.y, dz = zi - c.z;
      m = fminf(m, fmaf(dx, dx, fmaf(dy, dy, dz * dz)));
    }

    // ---- 2. u = 12th smallest of the 64 lane minima ----
    float u;
    {
      float v = m;
#pragma unroll
      for (int r = 0; r < KK; ++r) {
        float mm = v;
#pragma unroll
        for (int o = 1; o < 64; o <<= 1) mm = fminf(mm, __shfl_xor(mm, o));
        u = mm;
        v = (v == mm) ? BIG : v;
      }
    }

    float qd[KK], qw[KK];
#pragma unroll
    for (int k = 0; k < KK; ++k) { qd[k] = BIG; qw[k] = 0.f; }

    // ---- 3a. collect-scan seed region ----
#pragma unroll
    for (int s = 0; s < SEED / 64; ++s) {
      const float4 c = base[s * 64];
      const float dx = xi - c.x, dy = yi - c.y, dz = zi - c.z;
      const float d2 = fmaf(dx, dx, fmaf(dy, dy, dz * dz));
      if (d2 <= u) {
        const float w = fmaf(W0, fabsf(dx), fmaf(W1, fabsf(dy), W2 * fabsf(dz)));
        pinsert(qd, qw, d2, w);
      }
    }

    // ---- 3b. right collect-march ----
    int rp = lo + SEED;
    while (rp < n) {
      const int pos = rp + lane;
      const bool vld = pos < n;
      const float4 c = vld ? sv[pos] : make_float4(PADX, PADX, PADX, 0.f);
      const float dx = xi - c.x, dy = yi - c.y, dz = zi - c.z;
      const float d2 = vld ? fmaf(dx, dx, fmaf(dy, dy, dz * dz)) : BIG;
      if (d2 <= u) {
        const float w = fmaf(W0, fabsf(dx), fmaf(W1, fabsf(dy), W2 * fabsf(dz)));
        pinsert(qd, qw, d2, w);
      }
      const float xf = __shfl(c.x, 63);
      rp += 64;
      const float gap = xf - SLACK_ - xi;
      if (gap > 0.f && gap * gap > u) break;
    }

    // ---- 3c. left collect-march ----
    int lp = lo - 1;
    while (lp >= 0) {
      const int pos = lp - lane;
      const bool vld = pos >= 0;
      const float4 c = vld ? sv[pos] : make_float4(-PADX, -PADX, -PADX, 0.f);
      const float dx = xi - c.x, dy = yi - c.y, dz = zi - c.z;
      const float d2 = vld ? fmaf(dx, dx, fmaf(dy, dy, dz * dz)) : BIG;
      if (d2 <= u) {
        const float w = fmaf(W0, fabsf(dx), fmaf(W1, fabsf(dy), W2 * fabsf(dz)));
        pinsert(qd, qw, d2, w);
      }
      const float xf = __shfl(c.x, 63);
      lp -= 64;
      const float gap = xi - SLACK_ - xf;
      if (gap > 0.f && gap * gap > u) break;
    }

    // ---- 4. extract 12 smallest, accumulate w (first-lane tie-break) ----
    float acc = 0.f;
#pragma unroll
    for (int r = 0; r < KK; ++r) {
      float mm = qd[0];
#pragma unroll
      for (int o = 1; o < 64; o <<= 1) mm = fminf(mm, __shfl_xor(mm, o));
      const unsigned long long bal = __ballot(qd[0] == mm);
      if (qd[0] == mm && lane == __ffsll(bal) - 1) {
        acc += qw[0];
#pragma unroll
        for (int k = 0; k < KK - 1; ++k) { qd[k] = qd[k + 1]; qw[k] = qw[k + 1]; }
        qd[KK - 1] = BIG;
      }
    }

    // ---- 5. reduce + write ----
#pragma unroll
    for (int o = 1; o < 64; o <<= 1) acc += __shfl_xor(acc, o);
    if (lane == 0) {
      const float xw0 = W0 * xi + W1 * yi + W2 * zi;
      // 1 + 11/sqrt(2)
      out[orig] = bb + (xw0 * 8.778174593052022f + 0.5f * acc) * (1.0f / 12.0f);
    }
  }
}

extern "C" void kernel_launch(void* const* d_in, const int* in_sizes, int n_in,
                              void* d_out, int out_size, void* d_ws, size_t ws_size,
                              hipStream_t stream) {
  const float* p  = (const float*)d_in[0];
  const float* W  = (const float*)d_in[1];
  const float* bb = (const float*)d_in[2];
  float* out = (float*)d_out;

  const int n = in_sizes[0] / 3;   // 16384

  // ws: hist[2048] @0 | cnt[4]+qctr @8192 | cursor[2048] @8256 | sorted @16448
  int*    hist   = (int*)d_ws;
  int*    cnt    = (int*)((char*)d_ws + 8192);
  int*    qctr   = (int*)((char*)d_ws + 8240);
  int*    cursor = (int*)((char*)d_ws + 8256);
  float4* sorted = (float4*)((char*)d_ws + 16448);

  hipMemsetAsync((char*)d_ws + 8192, 0, 64, stream);   // cnt + qctr only
  sort_kernel<<<SORTB, STHR, 0, stream>>>(p, hist, cursor, cnt, sorted, n);
  query_kernel<<<2048, BLOCK, 0, stream>>>(sorted, W, bb, out, qctr, n);
}